// Round 7
// baseline (473.868 us; speedup 1.0000x reference)
//
#include <hip/hip_runtime.h>

// DynamicGraphAttention: B=16, L=256, D=128, F_IN=64, F_OUT=64
// v10b: single-kernel variant of v10 (no workspace / no setup kernel, in case
// the dual-kernel d_ws path caused the round-6 harness failure).
// Core change vs v8: h is NEVER staged in LDS. Phase-A A-fragments load
// straight from global into registers (wave w reads only its own 32 rows; no
// cross-wave h sharing exists) with immediate f32->f16 conversion. W keeps the
// known-good per-thread 4x4 register-transpose -> LDS path. 3 barriers total,
// LDS ~17.9KB, one (b,l) per block (4096 blocks).
constexpr int D_   = 128;
constexpr int FIN  = 64;
constexpr int FOUT = 64;
constexpr float ALPHA = 0.2f;

typedef _Float16 f16x8 __attribute__((ext_vector_type(8)));
typedef float    f32x4 __attribute__((ext_vector_type(4)));

__global__ __launch_bounds__(256, 4) void gat_kernel(
    const float* __restrict__ hg, const int* __restrict__ adjg,
    const float* __restrict__ Wg, const float* __restrict__ ag,
    float* __restrict__ outg)
{
    // sX: prologue = W^T f16 [o][64] swz((o&7)<<4) in first 8KB;
    //     phase B/C = WhT f16 [o][128] swz((o&7)<<4) (16KB)
    __shared__ __align__(16) unsigned short sX[128 * 64];   // 16 KB
    __shared__ float sEi[D_];
    __shared__ __align__(16) float sEj[D_];
    __shared__ float sL[D_];
    __shared__ float sMxW[4];
    // total ~17.9 KB

    const int tid  = threadIdx.x;
    const int lane = tid & 63;
    const int w    = tid >> 6;      // wave 0..3, owns rows [w*32, w*32+32)
    const int g    = lane >> 4;     // k-group 0..3
    const int m16  = lane & 15;
    const int row0 = w * 32 + m16;

    const long bl = blockIdx.x;
    const float* hp   = hg   + bl * (long)(D_ * FIN);
    const int*   adjp = adjg + bl * (long)(D_ * D_);
    float*       outp = outg + bl * (long)(D_ * FOUT);

    char* xb = (char*)sX;

    // ---------------- prologue ----------------
    // h A-fragments straight from global: rows w*32+mt*16+m16, cols kt*32+g*8..+8.
    // Convert f32->f16 immediately so the f32 temporaries don't live across phase A.
    f16x8 ha[2][2];   // [mt][kt]
    #pragma unroll
    for (int mt = 0; mt < 2; ++mt)
        #pragma unroll
        for (int kt = 0; kt < 2; ++kt) {
            const float* hb = hp + (w * 32 + mt * 16 + m16) * 64 + kt * 32 + g * 8;
            float4 v0 = *(const float4*)hb;
            float4 v1 = *(const float4*)(hb + 4);
            ha[mt][kt][0] = (_Float16)v0.x; ha[mt][kt][1] = (_Float16)v0.y;
            ha[mt][kt][2] = (_Float16)v0.z; ha[mt][kt][3] = (_Float16)v0.w;
            ha[mt][kt][4] = (_Float16)v1.x; ha[mt][kt][5] = (_Float16)v1.y;
            ha[mt][kt][6] = (_Float16)v1.z; ha[mt][kt][7] = (_Float16)v1.w;
        }
    // adj tile0 (A-frag layout: rows row0/row0+16, cols g*8..+8)
    int4 areg[4];
    {
        const int* a0 = adjp + row0 * D_ + g * 8;
        areg[0] = *(const int4*)(a0);
        areg[1] = *(const int4*)(a0 + 4);
        areg[2] = *(const int4*)(a0 + 16 * D_);
        areg[3] = *(const int4*)(a0 + 16 * D_ + 4);
    }
    // W: per-thread 4(f) x 4(o) register transpose -> xb first 8KB, conflict-free 8B writes.
    {
        const int f0 = (tid & 15) * 4;
        const int o0 = (tid >> 4) * 4;
        float4 r0 = *(const float4*)&Wg[(f0 + 0) * 64 + o0];
        float4 r1 = *(const float4*)&Wg[(f0 + 1) * 64 + o0];
        float4 r2 = *(const float4*)&Wg[(f0 + 2) * 64 + o0];
        float4 r3 = *(const float4*)&Wg[(f0 + 3) * 64 + o0];
        float col[4][4] = {{r0.x, r1.x, r2.x, r3.x}, {r0.y, r1.y, r2.y, r3.y},
                           {r0.z, r1.z, r2.z, r3.z}, {r0.w, r1.w, r2.w, r3.w}};
        #pragma unroll
        for (int c = 0; c < 4; ++c) {
            int o = o0 + c;
            union { _Float16 h[4]; uint2 u; } cv;
            cv.h[0] = (_Float16)col[c][0]; cv.h[1] = (_Float16)col[c][1];
            cv.h[2] = (_Float16)col[c][2]; cv.h[3] = (_Float16)col[c][3];
            int off = (o * 128 + f0 * 2) ^ ((o & 7) << 4);
            *(uint2*)(xb + off) = cv.u;
        }
    }
    __syncthreads();   // B1: W^T image visible

    // W^T B-fragments: o = nt*16+m16, f = kt*32+g*8..+8
    f16x8 wf[2][4];
    #pragma unroll
    for (int kt = 0; kt < 2; ++kt)
        #pragma unroll
        for (int nt = 0; nt < 4; ++nt) {
            int o = nt * 16 + m16;
            wf[kt][nt] = *(const f16x8*)(xb + ((o * 128 + kt * 64 + g * 16) ^ ((o & 7) << 4)));
        }

    // ---------------- phase A: Wh = h @ W via MFMA 16x16x32 f16 (all-register) ----------------
    f32x4 acc[2][4];
    #pragma unroll
    for (int mt = 0; mt < 2; ++mt)
        #pragma unroll
        for (int nt = 0; nt < 4; ++nt) acc[mt][nt] = (f32x4){0.f, 0.f, 0.f, 0.f};

    #pragma unroll
    for (int kt = 0; kt < 2; ++kt)
        #pragma unroll
        for (int mt = 0; mt < 2; ++mt)
            #pragma unroll
            for (int nt = 0; nt < 4; ++nt)
                acc[mt][nt] = __builtin_amdgcn_mfma_f32_16x16x32_f16(ha[mt][kt], wf[kt][nt], acc[mt][nt], 0, 0, 0);
    __syncthreads();   // B2: all W-image reads done before WhT overwrites xb

    // ---------------- phase B: e_i/e_j butterflies; WhT -> sX ----------------
    {
        float a1v[4], a2v[4];
        #pragma unroll
        for (int nt = 0; nt < 4; ++nt) {
            a1v[nt] = ag[nt * 16 + m16];        // 512B, L2-resident
            a2v[nt] = ag[FOUT + nt * 16 + m16];
        }
        float wmax = -3.0e38f;
        #pragma unroll
        for (int mt = 0; mt < 2; ++mt) {
            #pragma unroll
            for (int r = 0; r < 4; ++r) {
                float ei = 0.f, ej = 0.f;
                #pragma unroll
                for (int nt = 0; nt < 4; ++nt) {
                    float v = acc[mt][nt][r];
                    ei += v * a1v[nt];
                    ej += v * a2v[nt];
                }
                #pragma unroll
                for (int s = 1; s < 16; s <<= 1) {
                    ei += __shfl_xor(ei, s);
                    ej += __shfl_xor(ej, s);
                }
                int row = w * 32 + mt * 16 + g * 4 + r;   // D-frag: col=lane&15, row=(lane>>4)*4+reg
                if (m16 == 0) { sEi[row] = ei; sEj[row] = ej; }
                wmax = fmaxf(wmax, ej);
            }
        }
        wmax = fmaxf(wmax, __shfl_xor(wmax, 16));
        wmax = fmaxf(wmax, __shfl_xor(wmax, 32));
        if (lane == 0) sMxW[w] = wmax;

        // WhT f16 -> sX: [o][j] swz, 4 consecutive j per (mt,nt) = one 8B write
        #pragma unroll
        for (int mt = 0; mt < 2; ++mt) {
            int j0r = w * 32 + mt * 16 + g * 4;
            #pragma unroll
            for (int nt = 0; nt < 4; ++nt) {
                int o = nt * 16 + m16;
                union { _Float16 h[4]; uint2 u; } cv;
                cv.h[0] = (_Float16)acc[mt][nt][0];
                cv.h[1] = (_Float16)acc[mt][nt][1];
                cv.h[2] = (_Float16)acc[mt][nt][2];
                cv.h[3] = (_Float16)acc[mt][nt][3];
                int off = (o * 256 + j0r * 2) ^ ((o & 7) << 4);
                *(uint2*)(xb + off) = cv.u;
            }
        }
    }
    __syncthreads();   // B3: sEi/sEj/sMxW/WhT visible to all waves

    // ---------------- phase C: P in-register (A-frag layout) + P @ Wh via MFMA ----------------
    #pragma unroll
    for (int mt = 0; mt < 2; ++mt)
        #pragma unroll
        for (int nt = 0; nt < 4; ++nt) acc[mt][nt] = (f32x4){0.f, 0.f, 0.f, 0.f};

    const float ei0 = sEi[row0];
    const float ei1 = sEi[row0 + 16];
    const float mxj = fmaxf(fmaxf(sMxW[0], sMxW[1]), fmaxf(sMxW[2], sMxW[3]));
    float t0 = ei0 + mxj, t1 = ei1 + mxj;
    const float mi0 = t0 > 0.f ? t0 : ALPHA * t0;   // = max_j leaky(ei0+ej)
    const float mi1 = t1 > 0.f ? t1 : ALPHA * t1;
    float lp0 = 0.f, lp1 = 0.f;

    const int* aprow0 = adjp + row0 * D_ + g * 8;
    const int* aprow1 = aprow0 + 16 * D_;

    #pragma unroll
    for (int jt = 0; jt < 4; ++jt) {
        const int j0 = jt * 32;
        float4 ejA = *(const float4*)&sEj[j0 + g * 8];
        float4 ejB = *(const float4*)&sEj[j0 + g * 8 + 4];
        float ejv[8] = {ejA.x, ejA.y, ejA.z, ejA.w, ejB.x, ejB.y, ejB.z, ejB.w};
        int aa0[8] = {areg[0].x, areg[0].y, areg[0].z, areg[0].w,
                      areg[1].x, areg[1].y, areg[1].z, areg[1].w};
        int aa1[8] = {areg[2].x, areg[2].y, areg[2].z, areg[2].w,
                      areg[3].x, areg[3].y, areg[3].z, areg[3].w};
        f16x8 pa0, pa1;
        #pragma unroll
        for (int q = 0; q < 8; ++q) {
            float e0 = ei0 + ejv[q];
            e0 = e0 > 0.f ? e0 : ALPHA * e0;
            float p0 = (aa0[q] > 0) ? __expf(e0 - mi0) : 0.f;   // in (0,1]
            lp0 += p0;
            pa0[q] = (_Float16)p0;
            float e1 = ei1 + ejv[q];
            e1 = e1 > 0.f ? e1 : ALPHA * e1;
            float p1 = (aa1[q] > 0) ? __expf(e1 - mi1) : 0.f;
            lp1 += p1;
            pa1[q] = (_Float16)p1;
        }
        if (jt < 3) {
            const int* n0 = aprow0 + (jt + 1) * 32;
            const int* n1 = aprow1 + (jt + 1) * 32;
            areg[0] = *(const int4*)(n0);
            areg[1] = *(const int4*)(n0 + 4);
            areg[2] = *(const int4*)(n1);
            areg[3] = *(const int4*)(n1 + 4);
        }
        f16x8 wb[4];
        #pragma unroll
        for (int nt = 0; nt < 4; ++nt) {
            int o = nt * 16 + m16;
            wb[nt] = *(const f16x8*)(xb + ((o * 256 + j0 * 2 + g * 16) ^ ((o & 7) << 4)));
        }
        #pragma unroll
        for (int nt = 0; nt < 4; ++nt) {
            acc[0][nt] = __builtin_amdgcn_mfma_f32_16x16x32_f16(pa0, wb[nt], acc[0][nt], 0, 0, 0);
            acc[1][nt] = __builtin_amdgcn_mfma_f32_16x16x32_f16(pa1, wb[nt], acc[1][nt], 0, 0, 0);
        }
    }

    // row sums across g-lane groups, exchange via sL (same-wave read below)
    lp0 += __shfl_xor(lp0, 16); lp0 += __shfl_xor(lp0, 32);
    lp1 += __shfl_xor(lp1, 16); lp1 += __shfl_xor(lp1, 32);
    if (g == 0) {
        sL[row0]      = lp0;
        sL[row0 + 16] = lp1;
    }

    // ---------------- epilogue: divide by row sum, write out ----------------
    #pragma unroll
    for (int mtx = 0; mtx < 2; ++mtx) {
        #pragma unroll
        for (int r = 0; r < 4; ++r) {
            int row = w * 32 + mtx * 16 + g * 4 + r;
            float inv = 1.0f / sL[row];
            #pragma unroll
            for (int nt = 0; nt < 4; ++nt)
                outp[row * 64 + nt * 16 + m16] = acc[mtx][nt][r] * inv;
        }
    }
}

extern "C" void kernel_launch(void* const* d_in, const int* in_sizes, int n_in,
                              void* d_out, int out_size, void* d_ws, size_t ws_size,
                              hipStream_t stream) {
    const float* h   = (const float*)d_in[0];
    const int*   adj = (const int*)d_in[1];
    const float* W   = (const float*)d_in[2];
    const float* a   = (const float*)d_in[3];
    float*       out = (float*)d_out;
    gat_kernel<<<dim3(16 * 256), dim3(256), 0, stream>>>(h, adj, W, a, out);
}